// Round 2
// baseline (472.092 us; speedup 1.0000x reference)
//
#include <hip/hip_runtime.h>

#define NXd 2048
#define NYd 2048

typedef int   i4 __attribute__((ext_vector_type(4)));
typedef float f4 __attribute__((ext_vector_type(4)));

// ---------------------------------------------------------------------------
// Kernel 1: per-row flags  row_in[y] = any(lay[y,:]==1), row_out[y] = any(==3)
// ---------------------------------------------------------------------------
__global__ __launch_bounds__(256) void row_flags_kernel(const int* __restrict__ lay,
                                                        int* __restrict__ rin,
                                                        int* __restrict__ rout) {
    const int y = blockIdx.x;
    const i4* row = (const i4*)(lay + (size_t)y * NXd);
    int fin = 0, fout = 0;
    for (int x = threadIdx.x; x < NXd / 4; x += 256) {
        const i4 L = row[x];
        #pragma unroll
        for (int e = 0; e < 4; ++e) { fin |= (L[e] == 1); fout |= (L[e] == 3); }
    }
    __shared__ int s_in, s_out;
    if (threadIdx.x == 0) { s_in = 0; s_out = 0; }
    __syncthreads();
    const unsigned long long bi = __ballot(fin);
    const unsigned long long bo = __ballot(fout);
    if ((threadIdx.x & 63) == 0) {
        if (bi) atomicOr(&s_in, 1);
        if (bo) atomicOr(&s_out, 1);
    }
    __syncthreads();
    if (threadIdx.x == 0) { rin[y] = s_in; rout[y] = s_out; }
}

// ---------------------------------------------------------------------------
// Kernel 2: pure streaming — G_bc_mask (3 planes) + G_bc_v (6 planes).
// 4 pixels per thread, all loads/stores vectorized & aligned.
// ---------------------------------------------------------------------------
__global__ __launch_bounds__(256) void mask_kernel(const int* __restrict__ lay,
                                                   const int* __restrict__ rin,
                                                   const int* __restrict__ rout,
                                                   float* __restrict__ out) {
    const size_t NN = (size_t)NXd * NYd;
    const int g = blockIdx.x * 256 + threadIdx.x;      // 0 .. NN/4-1
    const int x4 = (g * 4) & (NXd - 1);
    const int y  = (g * 4) >> 11;
    const i4 L = ((const i4*)lay)[g];
    const int riny = rin[y], routy = rout[y];

    f4 m0, m1, m2, g0v, g1v, g2v, valv, zv;
    #pragma unroll
    for (int e = 0; e < 4; ++e) {
        const int Le = L[e];
        const float gb = (Le == 2) ? 0.f : 1.f;
        float gu = gb, gv = gb, gp = gb, valu = 0.f;
        if (x4 == 0 && e == 0 && riny)          { gu = 0.f; gv = 0.f; valu = 3.f; }
        if (x4 == NXd - 4 && e == 3 && routy)   { gp = 0.f; }
        const float gz   = (Le > 3) ? 0.f : 1.f;
        const float code = (Le > 3) ? (float)Le : 0.f;
        m0[e] = gu * gz + code;
        m1[e] = gv * gz + code;
        m2[e] = gp * gz + code;
        g0v[e] = gu; g1v[e] = gv; g2v[e] = gp;
        valv[e] = valu; zv[e] = 0.f;
    }

    f4* out_mask = (f4*)(out + (size_t)9 * 2046 * 2046);
    f4* out_gbcv = out_mask + 3 * (NN / 4);
    const size_t Q = NN / 4;
    out_mask[0 * Q + g] = m0;
    out_mask[1 * Q + g] = m1;
    out_mask[2 * Q + g] = m2;
    out_gbcv[0 * Q + g] = g0v;
    out_gbcv[1 * Q + g] = g1v;
    out_gbcv[2 * Q + g] = g2v;
    out_gbcv[3 * Q + g] = valv;
    out_gbcv[4 * Q + g] = zv;
    out_gbcv[5 * Q + g] = zv;
}

// ---------------------------------------------------------------------------
// Kernel 3: stencil — 9 loss planes. 4 interior pixels per thread.
// ---------------------------------------------------------------------------
__global__ __launch_bounds__(256) void loss_kernel(const int* __restrict__ lay,
                                                   const float* __restrict__ flow,
                                                   const int* __restrict__ rin,
                                                   const int* __restrict__ rout,
                                                   float* __restrict__ out) {
    const size_t NN = (size_t)NXd * NYd;
    const int g = blockIdx.x * 256 + threadIdx.x;   // 0..511: x-group within row
    const int y = blockIdx.y + 1;                   // 1..2046
    const int x4 = g * 4;
    const size_t rowC = (size_t)y * NXd;
    const int gi = (int)(rowC >> 2) + g;
    const int R = NXd / 4;

    const i4 LC4 = ((const i4*)lay)[gi];
    const i4 LN4 = ((const i4*)lay)[gi - R];
    const i4 LS4 = ((const i4*)lay)[gi + R];
    const int LW = (g > 0)   ? lay[rowC + x4 - 1] : 0;
    const int LE = (g < 511) ? lay[rowC + x4 + 4] : 0;

    const float* __restrict__ f0 = flow;
    const float* __restrict__ f1 = flow + NN;
    const float* __restrict__ f2 = flow + 2 * NN;

    f4 uC = ((const f4*)f0)[gi], uN = ((const f4*)f0)[gi - R], uS = ((const f4*)f0)[gi + R];
    f4 vC = ((const f4*)f1)[gi], vN = ((const f4*)f1)[gi - R], vS = ((const f4*)f1)[gi + R];
    f4 pC = ((const f4*)f2)[gi], pN = ((const f4*)f2)[gi - R], pS = ((const f4*)f2)[gi + R];
    float uWs = (g > 0)   ? f0[rowC + x4 - 1] : 0.f;
    float vWs = (g > 0)   ? f1[rowC + x4 - 1] : 0.f;
    float pWs = (g > 0)   ? f2[rowC + x4 - 1] : 0.f;
    float uEs = (g < 511) ? f0[rowC + x4 + 4] : 0.f;
    float vEs = (g < 511) ? f1[rowC + x4 + 4] : 0.f;
    float pEs = (g < 511) ? f2[rowC + x4 + 4] : 0.f;

    // apply no-slip (lay==2) masking
    #pragma unroll
    for (int e = 0; e < 4; ++e) {
        if (LC4[e] == 2) { uC[e] = 0.f; vC[e] = 0.f; pC[e] = 0.f; }
        if (LN4[e] == 2) { uN[e] = 0.f; vN[e] = 0.f; pN[e] = 0.f; }
        if (LS4[e] == 2) { uS[e] = 0.f; vS[e] = 0.f; pS[e] = 0.f; }
    }
    if (LW == 2) { uWs = 0.f; vWs = 0.f; pWs = 0.f; }
    if (LE == 2) { uEs = 0.f; vEs = 0.f; pEs = 0.f; }

    // boundary-condition overrides (col 0 inflow, col NX-1 outflow) — these
    // elements are never outputs, only west/east neighbors of x=1 / x=2046.
    const int riny = rin[y], routy = rout[y];
    if (g == 0 && riny)     { uC[0] = 3.f; vC[0] = 0.f; }
    if (g == 511 && routy)  { pC[3] = 0.f; }

    const float invh = 20470.0f;                       // 1/h, h = 0.1/2047
    const float nuh2 = 0.05f * 20470.0f * 20470.0f;    // nu/h^2

    const size_t PS = (size_t)2046 * 2046;
    float* __restrict__ out_loss = out;

    #pragma unroll
    for (int e = 0; e < 4; ++e) {
        const int x = x4 + e;
        if (x < 1 || x > NXd - 2) continue;            // only g==0/e==0, g==511/e==3
        const float uW = (e == 0) ? uWs : uC[e - 1];
        const float uE = (e == 3) ? uEs : uC[e + 1];
        const float vW = (e == 0) ? vWs : vC[e - 1];
        const float vE = (e == 3) ? vEs : vC[e + 1];
        const float pW = (e == 0) ? pWs : pC[e - 1];
        const float pE = (e == 3) ? pEs : pC[e + 1];

        const float dxu = 0.5f * (uE - uW);
        const float dyu = 0.5f * (uS[e] - uN[e]);
        const float dxv = 0.5f * (vE - vW);
        const float dyv = 0.5f * (vS[e] - vN[e]);
        const float lapu = uN[e] + uS[e] + uW + uE - 4.f * uC[e];
        const float lapv = vN[e] + vS[e] + vW + vE - 4.f * vC[e];

        const int cs = (LC4[e] > 3) ? LC4[e] : 0;
        float dpx, dpy;
        if (cs == 4 || cs == 8 || cs == 11)       dpx = pE - pC[e];
        else if (cs == 6 || cs == 9 || cs == 10)  dpx = pC[e] - pW;
        else                                      dpx = 0.5f * (pE - pW);
        if (cs == 7 || cs == 10 || cs == 11)      dpy = pN[e] - pC[e];
        else if (cs == 5 || cs == 8 || cs == 9)   dpy = pC[e] - pS[e];
        else                                      dpy = 0.5f * (pS[e] - pN[e]);

        const float zm = (LC4[e] == 2) ? 0.f : 1.f;
        const float mu   = zm * ((uC[e] * dxu + vC[e] * dyu + dpx) * invh - lapu * nuh2);
        const float mv   = zm * ((uC[e] * dxv + vC[e] * dyv + dpy) * invh - lapv * nuh2);
        const float cont = zm * ((dxu + dyv) * invh);

        const size_t li = (size_t)(y - 1) * 2046 + (x - 1);
        out_loss[0 * PS + li] = mu;
        out_loss[1 * PS + li] = mu;
        out_loss[2 * PS + li] = mu;
        out_loss[3 * PS + li] = mv;
        out_loss[4 * PS + li] = mv;
        out_loss[5 * PS + li] = mv;
        out_loss[6 * PS + li] = cont;
        out_loss[7 * PS + li] = cont;
        out_loss[8 * PS + li] = cont;
    }
}

extern "C" void kernel_launch(void* const* d_in, const int* in_sizes, int n_in,
                              void* d_out, int out_size, void* d_ws, size_t ws_size,
                              hipStream_t stream) {
    const int*   layout = (const int*)d_in[0];
    const float* flow   = (const float*)d_in[1];
    const int*   lay    = layout + (size_t)NYd * NXd;   // layout[0,1] channel
    float* out = (float*)d_out;
    int* rin  = (int*)d_ws;
    int* rout = rin + NYd;

    row_flags_kernel<<<NYd, 256, 0, stream>>>(lay, rin, rout);

    const size_t NN = (size_t)NXd * NYd;
    mask_kernel<<<(int)(NN / 4 / 256), 256, 0, stream>>>(lay, rin, rout, out);

    dim3 grid(2, NYd - 2, 1);
    loss_kernel<<<grid, dim3(256, 1, 1), 0, stream>>>(lay, flow, rin, rout, out);
}